// Round 10
// baseline (213.300 us; speedup 1.0000x reference)
//
#include <hip/hip_runtime.h>
#include <stdint.h>

typedef _Float16 f16x8 __attribute__((ext_vector_type(8)));
typedef float    f32x4 __attribute__((ext_vector_type(4)));

#define D 128

// ---------------- init: zero deg (all blocks) + int64/int32 detect (block 0) ----------------
__global__ void k_init(const uint32_t* __restrict__ e, uint32_t* __restrict__ flag,
                       uint4* __restrict__ deg4, int n4) {
  int t = blockIdx.x * blockDim.x + threadIdx.x;
  if (t < n4) deg4[t] = make_uint4(0u, 0u, 0u, 0u);
  if (blockIdx.x == 0) {
    __shared__ uint32_t red[256];
    uint32_t v = 0;
    for (int i = threadIdx.x; i < 1024; i += 256) v |= e[2 * i + 1];
    red[threadIdx.x] = v;
    __syncthreads();
    if (threadIdx.x == 0) {
      uint32_t a = 0;
#pragma unroll
      for (int i = 0; i < 256; ++i) a |= red[i];
      flag[0] = (a == 0u) ? 1u : 0u;   // 1 -> int64 words (stride 2), 0 -> int32
    }
  }
}

// One-shot W convert+transpose: wT[m][n][k] = W_m[k][n] as f16.  3 x 128 x 128.
__global__ void k_wcvt(const float* __restrict__ W0, const float* __restrict__ W1,
                       const float* __restrict__ W2, _Float16* __restrict__ wT) {
  int t = blockIdx.x * blockDim.x + threadIdx.x;   // 3*128*16 threads
  int m = t >> 11;
  int r = t & 2047;
  int n = r >> 4, k0 = (r & 15) * 8;
  const float* W = (m == 0) ? W0 : (m == 1) ? W1 : W2;
  f16x8 v;
#pragma unroll
  for (int j = 0; j < 8; ++j) v[j] = (_Float16)W[(k0 + j) * D + n];
  *reinterpret_cast<f16x8*>(wT + ((size_t)m * D + n) * D + k0) = v;
}

// Pack edges: packed[e] = (dst<<16) | src  (valid while N <= 65536)
__global__ void k_compact(const uint32_t* __restrict__ edges, const uint32_t* __restrict__ flag,
                          uint32_t* __restrict__ packed, int E) {
  int e = blockIdx.x * blockDim.x + threadIdx.x;
  if (e >= E) return;
  uint32_t f = flag[0];
  uint32_t s = edges[(size_t)e << f];
  uint32_t d = edges[((size_t)(E + e)) << f];
  packed[e] = (d << 16) | s;
}

// XCD-sliced degree count: slice = bid&7 rides round-robin block->XCD dispatch, so each
// slice's deg range gets atomics from ONE XCD's L2 only (no cross-XCD line bouncing).
__global__ __launch_bounds__(256) void k_count(const uint32_t* __restrict__ packed,
                                               uint32_t* __restrict__ deg, int E, int N) {
  const int slice = blockIdx.x & 7;
  const int chunk = blockIdx.x >> 3;
  const int nchunks = (int)(gridDim.x >> 3);
  const uint32_t lo = (uint32_t)(((uint64_t)N * slice) >> 3);
  const uint32_t hi = (uint32_t)(((uint64_t)N * (slice + 1)) >> 3);
  int per = (E + nchunks - 1) / nchunks;
  int e0 = chunk * per;
  int e1 = min(E, e0 + per);
  for (int e = e0 + (int)threadIdx.x; e < e1; e += 256) {
    uint32_t d = packed[e] >> 16;
    if (d >= lo && d < hi) atomicAdd(&deg[d], 1u);
  }
}

// ---------------- multi-block exclusive scan of deg -> rowptr/cursor (+dinv) ----------------
__global__ __launch_bounds__(256) void k_scan1(const uint32_t* __restrict__ deg,
                                               uint32_t* __restrict__ bsum, int N) {
  int i0 = blockIdx.x * 1024 + threadIdx.x * 4;
  uint32_t s = 0;
  if (i0 + 3 < N) {
    uint4 v = *reinterpret_cast<const uint4*>(deg + i0);
    s = v.x + v.y + v.z + v.w;
  } else {
    for (int j = 0; j < 4; ++j) if (i0 + j < N) s += deg[i0 + j];
  }
#pragma unroll
  for (int off = 1; off < 64; off <<= 1) s += __shfl_xor(s, off);
  __shared__ uint32_t ws[4];
  if ((threadIdx.x & 63) == 0) ws[threadIdx.x >> 6] = s;
  __syncthreads();
  if (threadIdx.x == 0) bsum[blockIdx.x] = ws[0] + ws[1] + ws[2] + ws[3];
}

__global__ void k_scan2(uint32_t* __restrict__ bsum, int nb) {
  int t = threadIdx.x;  // 64 threads
  uint32_t carry = 0;
  for (int base = 0; base < nb; base += 64) {
    uint32_t v = (base + t < nb) ? bsum[base + t] : 0u;
    uint32_t inc = v;
#pragma unroll
    for (int off = 1; off < 64; off <<= 1) {
      uint32_t u = __shfl_up(inc, off);
      if (t >= off) inc += u;
    }
    uint32_t ex = __shfl_up(inc, 1);
    if (t == 0) ex = 0u;
    if (base + t < nb) bsum[base + t] = carry + ex;
    carry += __shfl(inc, 63);
  }
}

__global__ __launch_bounds__(256) void k_scan3(const uint32_t* __restrict__ deg,
                                               const uint32_t* __restrict__ bsum,
                                               uint32_t* __restrict__ rowptr,
                                               uint32_t* __restrict__ cursor,
                                               float* __restrict__ dinv, int N, int E) {
  int i0 = blockIdx.x * 1024 + threadIdx.x * 4;
  uint32_t v[4];
  uint32_t s = 0;
#pragma unroll
  for (int j = 0; j < 4; ++j) { v[j] = (i0 + j < N) ? deg[i0 + j] : 0u; s += v[j]; }
  int lane = threadIdx.x & 63, wid = threadIdx.x >> 6;
  uint32_t inc = s;
#pragma unroll
  for (int off = 1; off < 64; off <<= 1) {
    uint32_t u = __shfl_up(inc, off);
    if (lane >= off) inc += u;
  }
  __shared__ uint32_t wsum[4];
  if (lane == 63) wsum[wid] = inc;
  __syncthreads();
  uint32_t woff = 0;
#pragma unroll
  for (int k = 0; k < 4; ++k) if (k < wid) woff += wsum[k];
  uint32_t run = bsum[blockIdx.x] + woff + (inc - s);
#pragma unroll
  for (int j = 0; j < 4; ++j) {
    int i = i0 + j;
    if (i < N) {
      rowptr[i] = run;
      cursor[i] = run;
      dinv[i] = rsqrtf((float)v[j] + 1.0f);
    }
    run += v[j];
  }
  if (blockIdx.x == 0 && threadIdx.x == 0) rowptr[N] = (uint32_t)E;
}

// XCD-sliced CSR fill: each slice's cursor range + csr output region is written by one
// XCD only -> L2-local atomics, full-line writebacks.
__global__ __launch_bounds__(256) void k_fill(const uint32_t* __restrict__ packed,
                                              uint32_t* __restrict__ cursor,
                                              uint16_t* __restrict__ csr, int E, int N) {
  const int slice = blockIdx.x & 7;
  const int chunk = blockIdx.x >> 3;
  const int nchunks = (int)(gridDim.x >> 3);
  const uint32_t lo = (uint32_t)(((uint64_t)N * slice) >> 3);
  const uint32_t hi = (uint32_t)(((uint64_t)N * (slice + 1)) >> 3);
  int per = (E + nchunks - 1) / nchunks;
  int e0 = chunk * per;
  int e1 = min(E, e0 + per);
  for (int e = e0 + (int)threadIdx.x; e < e1; e += 256) {
    uint32_t p = packed[e];
    uint32_t d = p >> 16;
    if (d >= lo && d < hi) {
      uint32_t pos = atomicAdd(&cursor[d], 1u);
      csr[pos] = (uint16_t)(p & 0xFFFFu);
    }
  }
}

// ---------------- GEMM: out16[N,128] = A[N,128] @ W (A f32; W pre-transposed f16) ------
__global__ __launch_bounds__(256) void k_gemm(const float* __restrict__ A,
                                              const _Float16* __restrict__ wT,
                                              _Float16* __restrict__ out, int N)
{
  __shared__ alignas(16) _Float16 xs[64][136];
  __shared__ alignas(16) _Float16 wt[128][136];  // wt[n][k] = W[k][n]

  const int tid  = threadIdx.x;
  const int row0 = blockIdx.x * 64;

  for (int i = tid; i < 64 * 16; i += 256) {
    int r = i >> 4, c = (i & 15) * 8;
    int gr = row0 + r; if (gr >= N) gr = N - 1;
    const f32x4* p = reinterpret_cast<const f32x4*>(A + (size_t)gr * D + c);
    f32x4 a = p[0], b = p[1];
    f16x8 v;
#pragma unroll
    for (int j = 0; j < 4; ++j) { v[j] = (_Float16)a[j]; v[j + 4] = (_Float16)b[j]; }
    *reinterpret_cast<f16x8*>(&xs[r][c]) = v;
  }
  for (int i = tid; i < 128 * 16; i += 256) {
    int n = i >> 4, k0 = (i & 15) * 8;
    *reinterpret_cast<f16x8*>(&wt[n][k0]) =
        *reinterpret_cast<const f16x8*>(wT + (size_t)n * D + k0);
  }
  __syncthreads();

  const int wave = tid >> 6, lane = tid & 63;
  const int m16 = lane & 15, khi = lane >> 4;
  const int wrow = wave * 16;

  f32x4 acc[8] = {};
#pragma unroll
  for (int kk = 0; kk < 4; ++kk) {
    f16x8 a = *reinterpret_cast<const f16x8*>(&xs[wrow + m16][kk * 32 + khi * 8]);
#pragma unroll
    for (int c = 0; c < 8; ++c) {
      f16x8 b = *reinterpret_cast<const f16x8*>(&wt[c * 16 + m16][kk * 32 + khi * 8]);
      acc[c] = __builtin_amdgcn_mfma_f32_16x16x32_f16(a, b, acc[c], 0, 0, 0);
    }
  }

#pragma unroll
  for (int c = 0; c < 8; ++c) {
#pragma unroll
    for (int j = 0; j < 4; ++j) {
      int gr = row0 + wrow + khi * 4 + j;
      if (gr < N) out[(size_t)gr * D + c * 16 + m16] = (_Float16)acc[c][j];
    }
  }
}

// Dual GEMM, f32 out + bias: Oa = A@Wa + ba, Ob = A@Wb + bb (A f16; wT pre-transposed f16)
__global__ __launch_bounds__(256) void k_gemm2o(const _Float16* __restrict__ A,
                                                const _Float16* __restrict__ wTa,
                                                const _Float16* __restrict__ wTb,
                                                const float* __restrict__ ba,
                                                const float* __restrict__ bb,
                                                float* __restrict__ Oa,
                                                float* __restrict__ Ob, int N)
{
  __shared__ alignas(16) _Float16 xs[64][136];
  __shared__ alignas(16) _Float16 wt[128][136];

  const int tid  = threadIdx.x;
  const int row0 = blockIdx.x * 64;

  for (int i = tid; i < 64 * 16; i += 256) {
    int r = i >> 4, c = (i & 15) * 8;
    int gr = row0 + r; if (gr >= N) gr = N - 1;
    *reinterpret_cast<f16x8*>(&xs[r][c]) =
        *reinterpret_cast<const f16x8*>(A + (size_t)gr * D + c);
  }

  const int wave = tid >> 6, lane = tid & 63;
  const int m16 = lane & 15, khi = lane >> 4;
  const int wrow = wave * 16;

#pragma unroll
  for (int m = 0; m < 2; ++m) {
    const _Float16* wT = m ? wTb : wTa;
    const float* bias = m ? bb : ba;
    float* out = m ? Ob : Oa;
    if (m) __syncthreads();  // prior compute's LDS reads done before overwrite
    for (int i = tid; i < 128 * 16; i += 256) {
      int n = i >> 4, k0 = (i & 15) * 8;
      *reinterpret_cast<f16x8*>(&wt[n][k0]) =
          *reinterpret_cast<const f16x8*>(wT + (size_t)n * D + k0);
    }
    __syncthreads();

    f32x4 acc[8] = {};
#pragma unroll
    for (int kk = 0; kk < 4; ++kk) {
      f16x8 a = *reinterpret_cast<const f16x8*>(&xs[wrow + m16][kk * 32 + khi * 8]);
#pragma unroll
      for (int c = 0; c < 8; ++c) {
        f16x8 b = *reinterpret_cast<const f16x8*>(&wt[c * 16 + m16][kk * 32 + khi * 8]);
        acc[c] = __builtin_amdgcn_mfma_f32_16x16x32_f16(a, b, acc[c], 0, 0, 0);
      }
    }
#pragma unroll
    for (int c = 0; c < 8; ++c) {
      float bv = bias[c * 16 + m16];
#pragma unroll
      for (int j = 0; j < 4; ++j) {
        int gr = row0 + wrow + khi * 4 + j;
        if (gr < N) out[(size_t)gr * D + c * 16 + m16] = acc[c][j] + bv;
      }
    }
  }
}

// ---------------- gather-aggregate: out = Â G (+bias, +ReLU optional), f16 out ----------
// out[n] = sum_{e: dst=n} G[src_e]*dinv[src]*dinv[n] + G[n]*dinv[n]^2 (+ bias)
// 32 threads/node = 2 edge-teams x 16 lanes. Each team gathers half the edge list
// (full 256B rows, coalesced); teams combine via one shfl_xor(16) per accumulator.
// Halves the serial edge chain (latency-bound fix); 8-deep unroll per team.
template <int RELU, int BIAS>
__global__ __launch_bounds__(256) void k_agg(
    const _Float16* __restrict__ G,
    const uint32_t* __restrict__ rowptr, const uint16_t* __restrict__ csr,
    const float* __restrict__ dinv, const float* __restrict__ bias,
    _Float16* __restrict__ out, int N)
{
  int t = blockIdx.x * blockDim.x + threadIdx.x;
  int n = t >> 5;                      // 32 threads per node
  if (n >= N) return;                  // uniform across the 32-lane group
  const int team = (threadIdx.x >> 4) & 1;
  const int c0 = (t & 15) * 8;

  uint32_t j0 = rowptr[n], j1 = rowptr[n + 1];
  uint32_t half = (j1 - j0 + 1) >> 1;
  uint32_t tj0 = j0 + (team ? half : 0u);
  uint32_t tj1 = team ? j1 : j0 + half;
  float dn = dinv[n];
  float acc[8] = {};
  uint32_t j = tj0;
  for (; j + 8 <= tj1; j += 8) {
    uint32_t s[8];
    float ww[8];
    f16x8 h[8];
#pragma unroll
    for (int u = 0; u < 8; ++u) s[u] = csr[j + u];
#pragma unroll
    for (int u = 0; u < 8; ++u) {
      ww[u] = dinv[s[u]] * dn;
      h[u] = *reinterpret_cast<const f16x8*>(G + (size_t)s[u] * D + c0);
    }
#pragma unroll
    for (int u = 0; u < 8; ++u)
#pragma unroll
      for (int q = 0; q < 8; ++q) acc[q] += (float)h[u][q] * ww[u];
  }
  for (; j + 4 <= tj1; j += 4) {
    uint32_t s0 = csr[j], s1 = csr[j + 1], s2 = csr[j + 2], s3 = csr[j + 3];
    float w0 = dinv[s0] * dn, w1 = dinv[s1] * dn, w2 = dinv[s2] * dn, w3 = dinv[s3] * dn;
    f16x8 h0 = *reinterpret_cast<const f16x8*>(G + (size_t)s0 * D + c0);
    f16x8 h1 = *reinterpret_cast<const f16x8*>(G + (size_t)s1 * D + c0);
    f16x8 h2 = *reinterpret_cast<const f16x8*>(G + (size_t)s2 * D + c0);
    f16x8 h3 = *reinterpret_cast<const f16x8*>(G + (size_t)s3 * D + c0);
#pragma unroll
    for (int q = 0; q < 8; ++q)
      acc[q] += ((float)h0[q] * w0 + (float)h1[q] * w1) + ((float)h2[q] * w2 + (float)h3[q] * w3);
  }
  for (; j < tj1; ++j) {
    uint32_t s0 = csr[j];
    float w0 = dinv[s0] * dn;
    f16x8 h0 = *reinterpret_cast<const f16x8*>(G + (size_t)s0 * D + c0);
#pragma unroll
    for (int q = 0; q < 8; ++q) acc[q] += (float)h0[q] * w0;
  }

  // combine the two teams' partial sums (lane ^ 16 is the partner team, same c0)
#pragma unroll
  for (int q = 0; q < 8; ++q) acc[q] += __shfl_xor(acc[q], 16);

  if (team == 0) {
    float di2 = dn * dn;
    f16x8 g = *reinterpret_cast<const f16x8*>(G + (size_t)n * D + c0);
    f32x4 b0 = {}, b1 = {};
    if (BIAS) {
      const f32x4* bp = reinterpret_cast<const f32x4*>(bias + c0);
      b0 = bp[0]; b1 = bp[1];
    }
    f16x8 o;
#pragma unroll
    for (int q = 0; q < 8; ++q) {
      float bv = BIAS ? ((q < 4) ? b0[q] : b1[q - 4]) : 0.0f;
      float r = acc[q] + (float)g[q] * di2 + bv;
      if (RELU) r = r > 0.f ? r : 0.f;
      o[q] = (_Float16)r;
    }
    *reinterpret_cast<f16x8*>(out + (size_t)n * D + c0) = o;
  }
}

// ---------------- launcher ----------------
extern "C" void kernel_launch(void* const* d_in, const int* in_sizes, int n_in,
                              void* d_out, int out_size, void* d_ws, size_t ws_size,
                              hipStream_t stream) {
  const int N = in_sizes[0] / D;   // 50000  (u16 CSR requires N <= 65536)
  const int E = in_sizes[1] / 2;   // 800000

  const float* x        = (const float*)d_in[0];
  const uint32_t* edges = (const uint32_t*)d_in[1];
  const float* W1  = (const float*)d_in[2];
  const float* b1  = (const float*)d_in[3];
  const float* Wmu = (const float*)d_in[4];
  const float* bmu = (const float*)d_in[5];
  const float* Wls = (const float*)d_in[6];
  const float* bls = (const float*)d_in[7];
  float* out_mu = (float*)d_out;
  float* out_ls = out_mu + (size_t)N * D;

  // workspace carve
  char* w = (char*)d_ws;
  uint32_t* deg    = (uint32_t*)(w);                  // N u32
  uint32_t* flag   = (uint32_t*)(w + (256u << 10));   // 1 u32
  uint32_t* bsum   = (uint32_t*)(w + (320u << 10));   // <=64 u32
  uint32_t* rowptr = (uint32_t*)(w + (512u << 10));   // N+1 u32
  uint32_t* cursor = (uint32_t*)(w + (768u << 10));   // N u32
  float*    dinv   = (float*)(w + (1u << 20));        // N f32 (200KB)
  _Float16* wT     = (_Float16*)(w + (1280u << 10));  // 3*128*128 f16 (96KB)
  uint32_t* packed = (uint32_t*)(w + (2u << 20));     // E u32 (3.2MB)
  uint16_t* csr    = (uint16_t*)(w + (6u << 20));     // E u16 (1.6MB)
  _Float16* G16    = (_Float16*)(w + (8u << 20));     // N*D f16 (GEMM out; reused as hagg)
  _Float16* h16    = (_Float16*)(w + (21u << 20));    // N*D f16
  size_t need = (21u << 20) + (size_t)N * D * 2;
  if (ws_size < need || N > 65536) return;

  _Float16* wT1  = wT;
  _Float16* wTmu = wT + 128 * 128;
  _Float16* wTls = wT + 2 * 128 * 128;

  const int nDeg4 = (N + 3) / 4;
  const int nb = (N + 1023) / 1024;   // 49 for N=50000

  k_init<<<(nDeg4 + 255) / 256, 256, 0, stream>>>(edges, flag, (uint4*)deg, nDeg4);
  k_wcvt<<<24, 256, 0, stream>>>(W1, Wmu, Wls, wT);
  k_compact<<<(E + 255) / 256, 256, 0, stream>>>(edges, flag, packed, E);
  k_count<<<8 * 128, 256, 0, stream>>>(packed, deg, E, N);
  k_scan1<<<nb, 256, 0, stream>>>(deg, bsum, N);
  k_scan2<<<1, 64, 0, stream>>>(bsum, nb);
  k_scan3<<<nb, 256, 0, stream>>>(deg, bsum, rowptr, cursor, dinv, N, E);
  k_fill<<<8 * 128, 256, 0, stream>>>(packed, cursor, csr, E, N);

  const int gemmGrid = (N + 63) / 64;
  const int aggGrid  = (N * 32 + 255) / 256;

  // conv1: h = relu(Â(x@W1) + b1)
  k_gemm<<<gemmGrid, 256, 0, stream>>>(x, wT1, G16, N);
  k_agg<1, 1><<<aggGrid, 256, 0, stream>>>(G16, rowptr, csr, dinv, b1, h16, N);

  // shared aggregation: hagg = Â h   (linearity: Â(hW) = (Âh)W)
  k_agg<0, 0><<<aggGrid, 256, 0, stream>>>(h16, rowptr, csr, dinv,
                                           (const float*)nullptr, G16, N);

  // dual GEMM epilogue: out_mu = hagg@Wmu + bmu, out_ls = hagg@Wls + bls (f32)
  k_gemm2o<<<gemmGrid, 256, 0, stream>>>(G16, wTmu, wTls, bmu, bls, out_mu, out_ls, N);
}

// Round 11
// 207.746 us; speedup vs baseline: 1.0267x; 1.0267x over previous
//
#include <hip/hip_runtime.h>
#include <stdint.h>

typedef _Float16 f16x8 __attribute__((ext_vector_type(8)));
typedef float    f32x4 __attribute__((ext_vector_type(4)));

#define D 128

// ---------------- init: zero deg (all blocks) + int64/int32 detect (block 0) ----------------
__global__ void k_init(const uint32_t* __restrict__ e, uint32_t* __restrict__ flag,
                       uint4* __restrict__ deg4, int n4) {
  int t = blockIdx.x * blockDim.x + threadIdx.x;
  if (t < n4) deg4[t] = make_uint4(0u, 0u, 0u, 0u);
  if (blockIdx.x == 0) {
    __shared__ uint32_t red[256];
    uint32_t v = 0;
    for (int i = threadIdx.x; i < 1024; i += 256) v |= e[2 * i + 1];
    red[threadIdx.x] = v;
    __syncthreads();
    if (threadIdx.x == 0) {
      uint32_t a = 0;
#pragma unroll
      for (int i = 0; i < 256; ++i) a |= red[i];
      flag[0] = (a == 0u) ? 1u : 0u;   // 1 -> int64 words (stride 2), 0 -> int32
    }
  }
}

// One-shot W convert+transpose: wT[m][n][k] = W_m[k][n] as f16.  3 x 128 x 128.
__global__ void k_wcvt(const float* __restrict__ W0, const float* __restrict__ W1,
                       const float* __restrict__ W2, _Float16* __restrict__ wT) {
  int t = blockIdx.x * blockDim.x + threadIdx.x;   // 3*128*16 threads
  int m = t >> 11;
  int r = t & 2047;
  int n = r >> 4, k0 = (r & 15) * 8;
  const float* W = (m == 0) ? W0 : (m == 1) ? W1 : W2;
  f16x8 v;
#pragma unroll
  for (int j = 0; j < 8; ++j) v[j] = (_Float16)W[(k0 + j) * D + n];
  *reinterpret_cast<f16x8*>(wT + ((size_t)m * D + n) * D + k0) = v;
}

// Pack edges: packed[e] = (dst<<16) | src  (valid while N <= 65536)
__global__ void k_compact(const uint32_t* __restrict__ edges, const uint32_t* __restrict__ flag,
                          uint32_t* __restrict__ packed, int E) {
  int e = blockIdx.x * blockDim.x + threadIdx.x;
  if (e >= E) return;
  uint32_t f = flag[0];
  uint32_t s = edges[(size_t)e << f];
  uint32_t d = edges[((size_t)(E + e)) << f];
  packed[e] = (d << 16) | s;
}

// XCD-sliced degree count: slice = bid&7 rides round-robin block->XCD dispatch, so each
// slice's deg range gets atomics from ONE XCD's L2 only (no cross-XCD line bouncing).
__global__ __launch_bounds__(256) void k_count(const uint32_t* __restrict__ packed,
                                               uint32_t* __restrict__ deg, int E, int N) {
  const int slice = blockIdx.x & 7;
  const int chunk = blockIdx.x >> 3;
  const int nchunks = (int)(gridDim.x >> 3);
  const uint32_t lo = (uint32_t)(((uint64_t)N * slice) >> 3);
  const uint32_t hi = (uint32_t)(((uint64_t)N * (slice + 1)) >> 3);
  int per = (E + nchunks - 1) / nchunks;
  int e0 = chunk * per;
  int e1 = min(E, e0 + per);
  for (int e = e0 + (int)threadIdx.x; e < e1; e += 256) {
    uint32_t d = packed[e] >> 16;
    if (d >= lo && d < hi) atomicAdd(&deg[d], 1u);
  }
}

// ---------------- multi-block exclusive scan of deg -> rowptr/cursor (+dinv) ----------------
__global__ __launch_bounds__(256) void k_scan1(const uint32_t* __restrict__ deg,
                                               uint32_t* __restrict__ bsum, int N) {
  int i0 = blockIdx.x * 1024 + threadIdx.x * 4;
  uint32_t s = 0;
  if (i0 + 3 < N) {
    uint4 v = *reinterpret_cast<const uint4*>(deg + i0);
    s = v.x + v.y + v.z + v.w;
  } else {
    for (int j = 0; j < 4; ++j) if (i0 + j < N) s += deg[i0 + j];
  }
#pragma unroll
  for (int off = 1; off < 64; off <<= 1) s += __shfl_xor(s, off);
  __shared__ uint32_t ws[4];
  if ((threadIdx.x & 63) == 0) ws[threadIdx.x >> 6] = s;
  __syncthreads();
  if (threadIdx.x == 0) bsum[blockIdx.x] = ws[0] + ws[1] + ws[2] + ws[3];
}

__global__ void k_scan2(uint32_t* __restrict__ bsum, int nb) {
  int t = threadIdx.x;  // 64 threads
  uint32_t carry = 0;
  for (int base = 0; base < nb; base += 64) {
    uint32_t v = (base + t < nb) ? bsum[base + t] : 0u;
    uint32_t inc = v;
#pragma unroll
    for (int off = 1; off < 64; off <<= 1) {
      uint32_t u = __shfl_up(inc, off);
      if (t >= off) inc += u;
    }
    uint32_t ex = __shfl_up(inc, 1);
    if (t == 0) ex = 0u;
    if (base + t < nb) bsum[base + t] = carry + ex;
    carry += __shfl(inc, 63);
  }
}

__global__ __launch_bounds__(256) void k_scan3(const uint32_t* __restrict__ deg,
                                               const uint32_t* __restrict__ bsum,
                                               uint32_t* __restrict__ rowptr,
                                               uint32_t* __restrict__ cursor,
                                               float* __restrict__ dinv, int N, int E) {
  int i0 = blockIdx.x * 1024 + threadIdx.x * 4;
  uint32_t v[4];
  uint32_t s = 0;
#pragma unroll
  for (int j = 0; j < 4; ++j) { v[j] = (i0 + j < N) ? deg[i0 + j] : 0u; s += v[j]; }
  int lane = threadIdx.x & 63, wid = threadIdx.x >> 6;
  uint32_t inc = s;
#pragma unroll
  for (int off = 1; off < 64; off <<= 1) {
    uint32_t u = __shfl_up(inc, off);
    if (lane >= off) inc += u;
  }
  __shared__ uint32_t wsum[4];
  if (lane == 63) wsum[wid] = inc;
  __syncthreads();
  uint32_t woff = 0;
#pragma unroll
  for (int k = 0; k < 4; ++k) if (k < wid) woff += wsum[k];
  uint32_t run = bsum[blockIdx.x] + woff + (inc - s);
#pragma unroll
  for (int j = 0; j < 4; ++j) {
    int i = i0 + j;
    if (i < N) {
      rowptr[i] = run;
      cursor[i] = run;
      dinv[i] = rsqrtf((float)v[j] + 1.0f);
    }
    run += v[j];
  }
  if (blockIdx.x == 0 && threadIdx.x == 0) rowptr[N] = (uint32_t)E;
}

// XCD-sliced CSR fill: each slice's cursor range + csr output region is written by one
// XCD only -> L2-local atomics, full-line writebacks.
__global__ __launch_bounds__(256) void k_fill(const uint32_t* __restrict__ packed,
                                              uint32_t* __restrict__ cursor,
                                              uint16_t* __restrict__ csr, int E, int N) {
  const int slice = blockIdx.x & 7;
  const int chunk = blockIdx.x >> 3;
  const int nchunks = (int)(gridDim.x >> 3);
  const uint32_t lo = (uint32_t)(((uint64_t)N * slice) >> 3);
  const uint32_t hi = (uint32_t)(((uint64_t)N * (slice + 1)) >> 3);
  int per = (E + nchunks - 1) / nchunks;
  int e0 = chunk * per;
  int e1 = min(E, e0 + per);
  for (int e = e0 + (int)threadIdx.x; e < e1; e += 256) {
    uint32_t p = packed[e];
    uint32_t d = p >> 16;
    if (d >= lo && d < hi) {
      uint32_t pos = atomicAdd(&cursor[d], 1u);
      csr[pos] = (uint16_t)(p & 0xFFFFu);
    }
  }
}

// ---------------- GEMM: out16[N,128] = A[N,128] @ W (A f32; W pre-transposed f16) ------
__global__ __launch_bounds__(256) void k_gemm(const float* __restrict__ A,
                                              const _Float16* __restrict__ wT,
                                              _Float16* __restrict__ out, int N)
{
  __shared__ alignas(16) _Float16 xs[64][136];
  __shared__ alignas(16) _Float16 wt[128][136];  // wt[n][k] = W[k][n]

  const int tid  = threadIdx.x;
  const int row0 = blockIdx.x * 64;

  for (int i = tid; i < 64 * 16; i += 256) {
    int r = i >> 4, c = (i & 15) * 8;
    int gr = row0 + r; if (gr >= N) gr = N - 1;
    const f32x4* p = reinterpret_cast<const f32x4*>(A + (size_t)gr * D + c);
    f32x4 a = p[0], b = p[1];
    f16x8 v;
#pragma unroll
    for (int j = 0; j < 4; ++j) { v[j] = (_Float16)a[j]; v[j + 4] = (_Float16)b[j]; }
    *reinterpret_cast<f16x8*>(&xs[r][c]) = v;
  }
  for (int i = tid; i < 128 * 16; i += 256) {
    int n = i >> 4, k0 = (i & 15) * 8;
    *reinterpret_cast<f16x8*>(&wt[n][k0]) =
        *reinterpret_cast<const f16x8*>(wT + (size_t)n * D + k0);
  }
  __syncthreads();

  const int wave = tid >> 6, lane = tid & 63;
  const int m16 = lane & 15, khi = lane >> 4;
  const int wrow = wave * 16;

  f32x4 acc[8] = {};
#pragma unroll
  for (int kk = 0; kk < 4; ++kk) {
    f16x8 a = *reinterpret_cast<const f16x8*>(&xs[wrow + m16][kk * 32 + khi * 8]);
#pragma unroll
    for (int c = 0; c < 8; ++c) {
      f16x8 b = *reinterpret_cast<const f16x8*>(&wt[c * 16 + m16][kk * 32 + khi * 8]);
      acc[c] = __builtin_amdgcn_mfma_f32_16x16x32_f16(a, b, acc[c], 0, 0, 0);
    }
  }

#pragma unroll
  for (int c = 0; c < 8; ++c) {
#pragma unroll
    for (int j = 0; j < 4; ++j) {
      int gr = row0 + wrow + khi * 4 + j;
      if (gr < N) out[(size_t)gr * D + c * 16 + m16] = (_Float16)acc[c][j];
    }
  }
}

// Dual GEMM, f32 out + bias: Oa = A@Wa + ba, Ob = A@Wb + bb (A f16; wT pre-transposed f16)
__global__ __launch_bounds__(256) void k_gemm2o(const _Float16* __restrict__ A,
                                                const _Float16* __restrict__ wTa,
                                                const _Float16* __restrict__ wTb,
                                                const float* __restrict__ ba,
                                                const float* __restrict__ bb,
                                                float* __restrict__ Oa,
                                                float* __restrict__ Ob, int N)
{
  __shared__ alignas(16) _Float16 xs[64][136];
  __shared__ alignas(16) _Float16 wt[128][136];

  const int tid  = threadIdx.x;
  const int row0 = blockIdx.x * 64;

  for (int i = tid; i < 64 * 16; i += 256) {
    int r = i >> 4, c = (i & 15) * 8;
    int gr = row0 + r; if (gr >= N) gr = N - 1;
    *reinterpret_cast<f16x8*>(&xs[r][c]) =
        *reinterpret_cast<const f16x8*>(A + (size_t)gr * D + c);
  }

  const int wave = tid >> 6, lane = tid & 63;
  const int m16 = lane & 15, khi = lane >> 4;
  const int wrow = wave * 16;

#pragma unroll
  for (int m = 0; m < 2; ++m) {
    const _Float16* wT = m ? wTb : wTa;
    const float* bias = m ? bb : ba;
    float* out = m ? Ob : Oa;
    if (m) __syncthreads();  // prior compute's LDS reads done before overwrite
    for (int i = tid; i < 128 * 16; i += 256) {
      int n = i >> 4, k0 = (i & 15) * 8;
      *reinterpret_cast<f16x8*>(&wt[n][k0]) =
          *reinterpret_cast<const f16x8*>(wT + (size_t)n * D + k0);
    }
    __syncthreads();

    f32x4 acc[8] = {};
#pragma unroll
    for (int kk = 0; kk < 4; ++kk) {
      f16x8 a = *reinterpret_cast<const f16x8*>(&xs[wrow + m16][kk * 32 + khi * 8]);
#pragma unroll
      for (int c = 0; c < 8; ++c) {
        f16x8 b = *reinterpret_cast<const f16x8*>(&wt[c * 16 + m16][kk * 32 + khi * 8]);
        acc[c] = __builtin_amdgcn_mfma_f32_16x16x32_f16(a, b, acc[c], 0, 0, 0);
      }
    }
#pragma unroll
    for (int c = 0; c < 8; ++c) {
      float bv = bias[c * 16 + m16];
#pragma unroll
      for (int j = 0; j < 4; ++j) {
        int gr = row0 + wrow + khi * 4 + j;
        if (gr < N) out[(size_t)gr * D + c * 16 + m16] = acc[c][j] + bv;
      }
    }
  }
}

// ---------------- column-half-sliced gather-aggregate ----------------
// out[n, half-cols] = sum_{e: dst=n} G[src_e]*dinv[src]*dinv[n] + G[n]*dinv[n]^2 (+bias,+ReLU)
// Each half = 64 cols = 128B = EXACTLY one cache line (R6 lesson: never slice below line
// granularity). half = bid&1 rides round-robin dispatch: even XCDs serve half 0, odd serve
// half 1 -> per-XCD compulsory fill halves (12.8 -> 6.4MB); total fetch ~102 -> ~55MB.
// 8 lanes/node x 8 cols; gather = 8 lanes x 16B = one full line. 8-deep edge unroll.
template <int RELU, int BIAS>
__global__ __launch_bounds__(256) void k_agg(
    const _Float16* __restrict__ G,
    const uint32_t* __restrict__ rowptr, const uint16_t* __restrict__ csr,
    const float* __restrict__ dinv, const float* __restrict__ bias,
    _Float16* __restrict__ out, int N)
{
  const int half = blockIdx.x & 1;
  const int nb   = blockIdx.x >> 1;
  const int n    = nb * 32 + (threadIdx.x >> 3);
  if (n >= N) return;
  const int c0 = half * 64 + (threadIdx.x & 7) * 8;

  uint32_t j0 = rowptr[n], j1 = rowptr[n + 1];
  float dn = dinv[n];
  float acc[8] = {};
  uint32_t j = j0;
  for (; j + 8 <= j1; j += 8) {
    uint32_t s[8];
    float ww[8];
    f16x8 h[8];
#pragma unroll
    for (int u = 0; u < 8; ++u) s[u] = csr[j + u];
#pragma unroll
    for (int u = 0; u < 8; ++u) {
      ww[u] = dinv[s[u]] * dn;
      h[u] = *reinterpret_cast<const f16x8*>(G + (size_t)s[u] * D + c0);
    }
#pragma unroll
    for (int u = 0; u < 8; ++u)
#pragma unroll
      for (int q = 0; q < 8; ++q) acc[q] += (float)h[u][q] * ww[u];
  }
  for (; j + 4 <= j1; j += 4) {
    uint32_t s0 = csr[j], s1 = csr[j + 1], s2 = csr[j + 2], s3 = csr[j + 3];
    float w0 = dinv[s0] * dn, w1 = dinv[s1] * dn, w2 = dinv[s2] * dn, w3 = dinv[s3] * dn;
    f16x8 h0 = *reinterpret_cast<const f16x8*>(G + (size_t)s0 * D + c0);
    f16x8 h1 = *reinterpret_cast<const f16x8*>(G + (size_t)s1 * D + c0);
    f16x8 h2 = *reinterpret_cast<const f16x8*>(G + (size_t)s2 * D + c0);
    f16x8 h3 = *reinterpret_cast<const f16x8*>(G + (size_t)s3 * D + c0);
#pragma unroll
    for (int q = 0; q < 8; ++q)
      acc[q] += ((float)h0[q] * w0 + (float)h1[q] * w1) + ((float)h2[q] * w2 + (float)h3[q] * w3);
  }
  for (; j < j1; ++j) {
    uint32_t s0 = csr[j];
    float w0 = dinv[s0] * dn;
    f16x8 h0 = *reinterpret_cast<const f16x8*>(G + (size_t)s0 * D + c0);
#pragma unroll
    for (int q = 0; q < 8; ++q) acc[q] += (float)h0[q] * w0;
  }

  float di2 = dn * dn;
  f16x8 g = *reinterpret_cast<const f16x8*>(G + (size_t)n * D + c0);
  f32x4 b0 = {}, b1 = {};
  if (BIAS) {
    const f32x4* bp = reinterpret_cast<const f32x4*>(bias + c0);
    b0 = bp[0]; b1 = bp[1];
  }
  f16x8 o;
#pragma unroll
  for (int q = 0; q < 8; ++q) {
    float bv = BIAS ? ((q < 4) ? b0[q] : b1[q - 4]) : 0.0f;
    float r = acc[q] + (float)g[q] * di2 + bv;
    if (RELU) r = r > 0.f ? r : 0.f;
    o[q] = (_Float16)r;
  }
  *reinterpret_cast<f16x8*>(out + (size_t)n * D + c0) = o;
}

// ---------------- launcher ----------------
extern "C" void kernel_launch(void* const* d_in, const int* in_sizes, int n_in,
                              void* d_out, int out_size, void* d_ws, size_t ws_size,
                              hipStream_t stream) {
  const int N = in_sizes[0] / D;   // 50000  (u16 CSR requires N <= 65536)
  const int E = in_sizes[1] / 2;   // 800000

  const float* x        = (const float*)d_in[0];
  const uint32_t* edges = (const uint32_t*)d_in[1];
  const float* W1  = (const float*)d_in[2];
  const float* b1  = (const float*)d_in[3];
  const float* Wmu = (const float*)d_in[4];
  const float* bmu = (const float*)d_in[5];
  const float* Wls = (const float*)d_in[6];
  const float* bls = (const float*)d_in[7];
  float* out_mu = (float*)d_out;
  float* out_ls = out_mu + (size_t)N * D;

  // workspace carve
  char* w = (char*)d_ws;
  uint32_t* deg    = (uint32_t*)(w);                  // N u32
  uint32_t* flag   = (uint32_t*)(w + (256u << 10));   // 1 u32
  uint32_t* bsum   = (uint32_t*)(w + (320u << 10));   // <=64 u32
  uint32_t* rowptr = (uint32_t*)(w + (512u << 10));   // N+1 u32
  uint32_t* cursor = (uint32_t*)(w + (768u << 10));   // N u32
  float*    dinv   = (float*)(w + (1u << 20));        // N f32 (200KB)
  _Float16* wT     = (_Float16*)(w + (1280u << 10));  // 3*128*128 f16 (96KB)
  uint32_t* packed = (uint32_t*)(w + (2u << 20));     // E u32 (3.2MB)
  uint16_t* csr    = (uint16_t*)(w + (6u << 20));     // E u16 (1.6MB)
  _Float16* G16    = (_Float16*)(w + (8u << 20));     // N*D f16 (GEMM out; reused as hagg)
  _Float16* h16    = (_Float16*)(w + (21u << 20));    // N*D f16
  size_t need = (21u << 20) + (size_t)N * D * 2;
  if (ws_size < need || N > 65536) return;

  _Float16* wT1  = wT;
  _Float16* wTmu = wT + 128 * 128;
  _Float16* wTls = wT + 2 * 128 * 128;

  const int nDeg4 = (N + 3) / 4;
  const int nb = (N + 1023) / 1024;   // 49 for N=50000

  k_init<<<(nDeg4 + 255) / 256, 256, 0, stream>>>(edges, flag, (uint4*)deg, nDeg4);
  k_wcvt<<<24, 256, 0, stream>>>(W1, Wmu, Wls, wT);
  k_compact<<<(E + 255) / 256, 256, 0, stream>>>(edges, flag, packed, E);
  k_count<<<8 * 128, 256, 0, stream>>>(packed, deg, E, N);
  k_scan1<<<nb, 256, 0, stream>>>(deg, bsum, N);
  k_scan2<<<1, 64, 0, stream>>>(bsum, nb);
  k_scan3<<<nb, 256, 0, stream>>>(deg, bsum, rowptr, cursor, dinv, N, E);
  k_fill<<<8 * 128, 256, 0, stream>>>(packed, cursor, csr, E, N);

  const int gemmGrid = (N + 63) / 64;
  const int aggGrid  = ((N + 31) / 32) * 2;   // 2 column-halves

  // conv1: h = relu(Â(x@W1) + b1)
  k_gemm<<<gemmGrid, 256, 0, stream>>>(x, wT1, G16, N);
  k_agg<1, 1><<<aggGrid, 256, 0, stream>>>(G16, rowptr, csr, dinv, b1, h16, N);

  // shared aggregation: hagg = Â h   (linearity: Â(hW) = (Âh)W)
  k_agg<0, 0><<<aggGrid, 256, 0, stream>>>(h16, rowptr, csr, dinv,
                                           (const float*)nullptr, G16, N);

  // dual GEMM epilogue: out_mu = hagg@Wmu + bmu, out_ls = hagg@Wls + bls (f32)
  k_gemm2o<<<gemmGrid, 256, 0, stream>>>(G16, wTmu, wTls, bmu, bls, out_mu, out_ls, N);
}

// Round 12
// 196.276 us; speedup vs baseline: 1.0867x; 1.0584x over previous
//
#include <hip/hip_runtime.h>
#include <stdint.h>

typedef _Float16 f16x8 __attribute__((ext_vector_type(8)));
typedef float    f32x4 __attribute__((ext_vector_type(4)));

#define D 128
#define HISTCAP 6400

// ---------------- init: zero deg + int64/int32 detect (block 0) + W convert/transpose ----
__global__ void k_init(const uint32_t* __restrict__ e, uint32_t* __restrict__ flag,
                       uint4* __restrict__ deg4, int n4,
                       const float* __restrict__ W0, const float* __restrict__ W1,
                       const float* __restrict__ W2, _Float16* __restrict__ wT) {
  int t = blockIdx.x * blockDim.x + threadIdx.x;
  if (t < n4) deg4[t] = make_uint4(0u, 0u, 0u, 0u);
  if (t < 3 * 128 * 16) {   // wT[m][n][k] = W_m[k][n] as f16
    int m = t >> 11, r = t & 2047;
    int n = r >> 4, k0 = (r & 15) * 8;
    const float* W = (m == 0) ? W0 : (m == 1) ? W1 : W2;
    f16x8 v;
#pragma unroll
    for (int j = 0; j < 8; ++j) v[j] = (_Float16)W[(k0 + j) * D + n];
    *reinterpret_cast<f16x8*>(wT + ((size_t)m * D + n) * D + k0) = v;
  }
  if (blockIdx.x == 0) {
    __shared__ uint32_t red[256];
    uint32_t v = 0;
    for (int i = threadIdx.x; i < 1024; i += 256) v |= e[2 * i + 1];
    red[threadIdx.x] = v;
    __syncthreads();
    if (threadIdx.x == 0) {
      uint32_t a = 0;
#pragma unroll
      for (int i = 0; i < 256; ++i) a |= red[i];
      flag[0] = (a == 0u) ? 1u : 0u;   // 1 -> int64 words (stride 2), 0 -> int32
    }
  }
}

// Pack edges: packed[e] = (dst<<16) | src  (valid while N <= 65536)
__global__ void k_compact(const uint32_t* __restrict__ edges, const uint32_t* __restrict__ flag,
                          uint32_t* __restrict__ packed, int E) {
  int e = blockIdx.x * blockDim.x + threadIdx.x;
  if (e >= E) return;
  uint32_t f = flag[0];
  uint32_t s = edges[(size_t)e << f];
  uint32_t d = edges[((size_t)(E + e)) << f];
  packed[e] = (d << 16) | s;
}

// XCD-sliced degree count with LDS histogram: all hot atomics in LDS; merge is coalesced.
__global__ __launch_bounds__(256) void k_count(const uint32_t* __restrict__ packed,
                                               uint32_t* __restrict__ deg, int E, int N) {
  __shared__ uint32_t hist[HISTCAP];
  const int slice = blockIdx.x & 7;
  const int chunk = blockIdx.x >> 3;
  const int nchunks = (int)(gridDim.x >> 3);
  const uint32_t lo = (uint32_t)(((uint64_t)N * slice) >> 3);
  const uint32_t hi = (uint32_t)(((uint64_t)N * (slice + 1)) >> 3);
  const int len = (int)(hi - lo);
  const bool uselds = (len <= HISTCAP);
  if (uselds) {
    for (int i = threadIdx.x; i < len; i += 256) hist[i] = 0u;
    __syncthreads();
  }
  int per = (E + nchunks - 1) / nchunks;
  int e0 = chunk * per;
  int e1 = min(E, e0 + per);
  for (int e = e0 + (int)threadIdx.x; e < e1; e += 256) {
    uint32_t d = packed[e] >> 16;
    if (d >= lo && d < hi) {
      if (uselds) atomicAdd(&hist[d - lo], 1u);
      else        atomicAdd(&deg[d], 1u);
    }
  }
  if (uselds) {
    __syncthreads();
    for (int i = threadIdx.x; i < len; i += 256) {
      uint32_t v = hist[i];
      if (v) atomicAdd(&deg[lo + i], v);
    }
  }
}

// ---------------- multi-block exclusive scan of deg -> rowptr/cursor (+dinv) ----------------
__global__ __launch_bounds__(256) void k_scan1(const uint32_t* __restrict__ deg,
                                               uint32_t* __restrict__ bsum, int N) {
  int i0 = blockIdx.x * 1024 + threadIdx.x * 4;
  uint32_t s = 0;
  if (i0 + 3 < N) {
    uint4 v = *reinterpret_cast<const uint4*>(deg + i0);
    s = v.x + v.y + v.z + v.w;
  } else {
    for (int j = 0; j < 4; ++j) if (i0 + j < N) s += deg[i0 + j];
  }
#pragma unroll
  for (int off = 1; off < 64; off <<= 1) s += __shfl_xor(s, off);
  __shared__ uint32_t ws[4];
  if ((threadIdx.x & 63) == 0) ws[threadIdx.x >> 6] = s;
  __syncthreads();
  if (threadIdx.x == 0) bsum[blockIdx.x] = ws[0] + ws[1] + ws[2] + ws[3];
}

__global__ void k_scan2(uint32_t* __restrict__ bsum, int nb) {
  int t = threadIdx.x;  // 64 threads
  uint32_t carry = 0;
  for (int base = 0; base < nb; base += 64) {
    uint32_t v = (base + t < nb) ? bsum[base + t] : 0u;
    uint32_t inc = v;
#pragma unroll
    for (int off = 1; off < 64; off <<= 1) {
      uint32_t u = __shfl_up(inc, off);
      if (t >= off) inc += u;
    }
    uint32_t ex = __shfl_up(inc, 1);
    if (t == 0) ex = 0u;
    if (base + t < nb) bsum[base + t] = carry + ex;
    carry += __shfl(inc, 63);
  }
}

__global__ __launch_bounds__(256) void k_scan3(const uint32_t* __restrict__ deg,
                                               const uint32_t* __restrict__ bsum,
                                               uint32_t* __restrict__ rowptr,
                                               uint32_t* __restrict__ cursor,
                                               float* __restrict__ dinv, int N, int E) {
  int i0 = blockIdx.x * 1024 + threadIdx.x * 4;
  uint32_t v[4];
  uint32_t s = 0;
#pragma unroll
  for (int j = 0; j < 4; ++j) { v[j] = (i0 + j < N) ? deg[i0 + j] : 0u; s += v[j]; }
  int lane = threadIdx.x & 63, wid = threadIdx.x >> 6;
  uint32_t inc = s;
#pragma unroll
  for (int off = 1; off < 64; off <<= 1) {
    uint32_t u = __shfl_up(inc, off);
    if (lane >= off) inc += u;
  }
  __shared__ uint32_t wsum[4];
  if (lane == 63) wsum[wid] = inc;
  __syncthreads();
  uint32_t woff = 0;
#pragma unroll
  for (int k = 0; k < 4; ++k) if (k < wid) woff += wsum[k];
  uint32_t run = bsum[blockIdx.x] + woff + (inc - s);
#pragma unroll
  for (int j = 0; j < 4; ++j) {
    int i = i0 + j;
    if (i < N) {
      rowptr[i] = run;
      cursor[i] = run;
      dinv[i] = rsqrtf((float)v[j] + 1.0f);
    }
    run += v[j];
  }
  if (blockIdx.x == 0 && threadIdx.x == 0) rowptr[N] = (uint32_t)E;
}

// XCD-sliced CSR fill: each slice's cursor range + csr output region is written by one
// XCD only -> L2-local atomics, full-line writebacks.
__global__ __launch_bounds__(256) void k_fill(const uint32_t* __restrict__ packed,
                                              uint32_t* __restrict__ cursor,
                                              uint16_t* __restrict__ csr, int E, int N) {
  const int slice = blockIdx.x & 7;
  const int chunk = blockIdx.x >> 3;
  const int nchunks = (int)(gridDim.x >> 3);
  const uint32_t lo = (uint32_t)(((uint64_t)N * slice) >> 3);
  const uint32_t hi = (uint32_t)(((uint64_t)N * (slice + 1)) >> 3);
  int per = (E + nchunks - 1) / nchunks;
  int e0 = chunk * per;
  int e1 = min(E, e0 + per);
  for (int e = e0 + (int)threadIdx.x; e < e1; e += 256) {
    uint32_t p = packed[e];
    uint32_t d = p >> 16;
    if (d >= lo && d < hi) {
      uint32_t pos = atomicAdd(&cursor[d], 1u);
      csr[pos] = (uint16_t)(p & 0xFFFFu);
    }
  }
}

// ---------------- GEMM: out16[N,128] = A[N,128] @ W (A f32; W pre-transposed f16) ------
__global__ __launch_bounds__(256) void k_gemm(const float* __restrict__ A,
                                              const _Float16* __restrict__ wT,
                                              _Float16* __restrict__ out, int N)
{
  __shared__ alignas(16) _Float16 xs[64][136];
  __shared__ alignas(16) _Float16 wt[128][136];  // wt[n][k] = W[k][n]

  const int tid  = threadIdx.x;
  const int row0 = blockIdx.x * 64;

  for (int i = tid; i < 64 * 16; i += 256) {
    int r = i >> 4, c = (i & 15) * 8;
    int gr = row0 + r; if (gr >= N) gr = N - 1;
    const f32x4* p = reinterpret_cast<const f32x4*>(A + (size_t)gr * D + c);
    f32x4 a = p[0], b = p[1];
    f16x8 v;
#pragma unroll
    for (int j = 0; j < 4; ++j) { v[j] = (_Float16)a[j]; v[j + 4] = (_Float16)b[j]; }
    *reinterpret_cast<f16x8*>(&xs[r][c]) = v;
  }
  for (int i = tid; i < 128 * 16; i += 256) {
    int n = i >> 4, k0 = (i & 15) * 8;
    *reinterpret_cast<f16x8*>(&wt[n][k0]) =
        *reinterpret_cast<const f16x8*>(wT + (size_t)n * D + k0);
  }
  __syncthreads();

  const int wave = tid >> 6, lane = tid & 63;
  const int m16 = lane & 15, khi = lane >> 4;
  const int wrow = wave * 16;

  f32x4 acc[8] = {};
#pragma unroll
  for (int kk = 0; kk < 4; ++kk) {
    f16x8 a = *reinterpret_cast<const f16x8*>(&xs[wrow + m16][kk * 32 + khi * 8]);
#pragma unroll
    for (int c = 0; c < 8; ++c) {
      f16x8 b = *reinterpret_cast<const f16x8*>(&wt[c * 16 + m16][kk * 32 + khi * 8]);
      acc[c] = __builtin_amdgcn_mfma_f32_16x16x32_f16(a, b, acc[c], 0, 0, 0);
    }
  }

#pragma unroll
  for (int c = 0; c < 8; ++c) {
#pragma unroll
    for (int j = 0; j < 4; ++j) {
      int gr = row0 + wrow + khi * 4 + j;
      if (gr < N) out[(size_t)gr * D + c * 16 + m16] = (_Float16)acc[c][j];
    }
  }
}

// ---------------- column-half-sliced gather-aggregate (conv1) ----------------
// out[n, half-cols] = sum_{e: dst=n} G[src_e]*dinv[src]*dinv[n] + G[n]*dinv[n]^2 (+bias,+ReLU)
// half = 64 cols = 128B = one full cache line (R6 granularity lesson).
template <int RELU, int BIAS>
__global__ __launch_bounds__(256) void k_agg(
    const _Float16* __restrict__ G,
    const uint32_t* __restrict__ rowptr, const uint16_t* __restrict__ csr,
    const float* __restrict__ dinv, const float* __restrict__ bias,
    _Float16* __restrict__ out, int N)
{
  const int half = blockIdx.x & 1;
  const int nb   = blockIdx.x >> 1;
  const int n    = nb * 32 + (threadIdx.x >> 3);
  if (n >= N) return;
  const int c0 = half * 64 + (threadIdx.x & 7) * 8;

  uint32_t j0 = rowptr[n], j1 = rowptr[n + 1];
  float dn = dinv[n];
  float acc[8] = {};
  uint32_t j = j0;
  for (; j + 8 <= j1; j += 8) {
    uint32_t s[8];
    float ww[8];
    f16x8 h[8];
#pragma unroll
    for (int u = 0; u < 8; ++u) s[u] = csr[j + u];
#pragma unroll
    for (int u = 0; u < 8; ++u) {
      ww[u] = dinv[s[u]] * dn;
      h[u] = *reinterpret_cast<const f16x8*>(G + (size_t)s[u] * D + c0);
    }
#pragma unroll
    for (int u = 0; u < 8; ++u)
#pragma unroll
      for (int q = 0; q < 8; ++q) acc[q] += (float)h[u][q] * ww[u];
  }
  for (; j + 4 <= j1; j += 4) {
    uint32_t s0 = csr[j], s1 = csr[j + 1], s2 = csr[j + 2], s3 = csr[j + 3];
    float w0 = dinv[s0] * dn, w1 = dinv[s1] * dn, w2 = dinv[s2] * dn, w3 = dinv[s3] * dn;
    f16x8 h0 = *reinterpret_cast<const f16x8*>(G + (size_t)s0 * D + c0);
    f16x8 h1 = *reinterpret_cast<const f16x8*>(G + (size_t)s1 * D + c0);
    f16x8 h2 = *reinterpret_cast<const f16x8*>(G + (size_t)s2 * D + c0);
    f16x8 h3 = *reinterpret_cast<const f16x8*>(G + (size_t)s3 * D + c0);
#pragma unroll
    for (int q = 0; q < 8; ++q)
      acc[q] += ((float)h0[q] * w0 + (float)h1[q] * w1) + ((float)h2[q] * w2 + (float)h3[q] * w3);
  }
  for (; j < j1; ++j) {
    uint32_t s0 = csr[j];
    float w0 = dinv[s0] * dn;
    f16x8 h0 = *reinterpret_cast<const f16x8*>(G + (size_t)s0 * D + c0);
#pragma unroll
    for (int q = 0; q < 8; ++q) acc[q] += (float)h0[q] * w0;
  }

  float di2 = dn * dn;
  f16x8 g = *reinterpret_cast<const f16x8*>(G + (size_t)n * D + c0);
  f32x4 b0 = {}, b1 = {};
  if (BIAS) {
    const f32x4* bp = reinterpret_cast<const f32x4*>(bias + c0);
    b0 = bp[0]; b1 = bp[1];
  }
  f16x8 o;
#pragma unroll
  for (int q = 0; q < 8; ++q) {
    float bv = BIAS ? ((q < 4) ? b0[q] : b1[q - 4]) : 0.0f;
    float r = acc[q] + (float)g[q] * di2 + bv;
    if (RELU) r = r > 0.f ? r : 0.f;
    o[q] = (_Float16)r;
  }
  *reinterpret_cast<f16x8*>(out + (size_t)n * D + c0) = o;
}

// ---------------- fused: hagg tile (Â h) -> LDS -> dual GEMM -> out_mu/out_ls ----------
// Deletes the 12.8MB hagg write + 12.8MB read. Agg: 4 threads/node x 32 cols, 2-edge unroll.
__global__ __launch_bounds__(256) void k_aggemm(
    const _Float16* __restrict__ H,
    const uint32_t* __restrict__ rowptr, const uint16_t* __restrict__ csr,
    const float* __restrict__ dinv,
    const _Float16* __restrict__ wTa, const _Float16* __restrict__ wTb,
    const float* __restrict__ ba, const float* __restrict__ bb,
    float* __restrict__ Oa, float* __restrict__ Ob, int N)
{
  __shared__ alignas(16) _Float16 xs[64][136];
  __shared__ alignas(16) _Float16 wt[128][136];

  const int tid  = threadIdx.x;
  const int row0 = blockIdx.x * 64;

  // ---- agg phase ----
  {
    const int r  = tid >> 2;
    const int n  = row0 + r;
    const int c0 = (tid & 3) * 32;
    float acc[32] = {};
    if (n < N) {
      uint32_t j0 = rowptr[n], j1 = rowptr[n + 1];
      float dn = dinv[n];
      uint32_t j = j0;
      for (; j + 2 <= j1; j += 2) {
        uint32_t sA = csr[j], sB = csr[j + 1];
        float wA = dinv[sA] * dn, wB = dinv[sB] * dn;
        const f16x8* pA = reinterpret_cast<const f16x8*>(H + (size_t)sA * D + c0);
        const f16x8* pB = reinterpret_cast<const f16x8*>(H + (size_t)sB * D + c0);
        f16x8 a0 = pA[0], a1 = pA[1], a2 = pA[2], a3 = pA[3];
        f16x8 e0 = pB[0], e1 = pB[1], e2 = pB[2], e3 = pB[3];
#pragma unroll
        for (int q = 0; q < 8; ++q) {
          acc[q]      += (float)a0[q] * wA + (float)e0[q] * wB;
          acc[8 + q]  += (float)a1[q] * wA + (float)e1[q] * wB;
          acc[16 + q] += (float)a2[q] * wA + (float)e2[q] * wB;
          acc[24 + q] += (float)a3[q] * wA + (float)e3[q] * wB;
        }
      }
      if (j < j1) {
        uint32_t sA = csr[j];
        float wA = dinv[sA] * dn;
        const f16x8* pA = reinterpret_cast<const f16x8*>(H + (size_t)sA * D + c0);
        f16x8 a0 = pA[0], a1 = pA[1], a2 = pA[2], a3 = pA[3];
#pragma unroll
        for (int q = 0; q < 8; ++q) {
          acc[q]      += (float)a0[q] * wA;
          acc[8 + q]  += (float)a1[q] * wA;
          acc[16 + q] += (float)a2[q] * wA;
          acc[24 + q] += (float)a3[q] * wA;
        }
      }
      float di2 = dn * dn;
      const f16x8* gp = reinterpret_cast<const f16x8*>(H + (size_t)n * D + c0);
      f16x8 g0 = gp[0], g1 = gp[1], g2 = gp[2], g3 = gp[3];
#pragma unroll
      for (int q = 0; q < 8; ++q) {
        acc[q]      += (float)g0[q] * di2;
        acc[8 + q]  += (float)g1[q] * di2;
        acc[16 + q] += (float)g2[q] * di2;
        acc[24 + q] += (float)g3[q] * di2;
      }
    }
#pragma unroll
    for (int b = 0; b < 4; ++b) {
      f16x8 v;
#pragma unroll
      for (int q = 0; q < 8; ++q) v[q] = (_Float16)acc[b * 8 + q];
      *reinterpret_cast<f16x8*>(&xs[r][c0 + b * 8]) = v;
    }
  }

  // ---- dual GEMM phase (reads xs after barrier) ----
  const int wave = tid >> 6, lane = tid & 63;
  const int m16 = lane & 15, khi = lane >> 4;
  const int wrow = wave * 16;

#pragma unroll
  for (int m = 0; m < 2; ++m) {
    const _Float16* wT = m ? wTb : wTa;
    const float* bias = m ? bb : ba;
    float* out = m ? Ob : Oa;
    if (m) __syncthreads();  // prior compute's LDS reads done before wt overwrite
    for (int i = tid; i < 128 * 16; i += 256) {
      int n = i >> 4, k0 = (i & 15) * 8;
      *reinterpret_cast<f16x8*>(&wt[n][k0]) =
          *reinterpret_cast<const f16x8*>(wT + (size_t)n * D + k0);
    }
    __syncthreads();   // xs (m=0) and wt visible

    f32x4 acc[8] = {};
#pragma unroll
    for (int kk = 0; kk < 4; ++kk) {
      f16x8 a = *reinterpret_cast<const f16x8*>(&xs[wrow + m16][kk * 32 + khi * 8]);
#pragma unroll
      for (int c = 0; c < 8; ++c) {
        f16x8 b = *reinterpret_cast<const f16x8*>(&wt[c * 16 + m16][kk * 32 + khi * 8]);
        acc[c] = __builtin_amdgcn_mfma_f32_16x16x32_f16(a, b, acc[c], 0, 0, 0);
      }
    }
#pragma unroll
    for (int c = 0; c < 8; ++c) {
      float bv = bias[c * 16 + m16];
#pragma unroll
      for (int j = 0; j < 4; ++j) {
        int gr = row0 + wrow + khi * 4 + j;
        if (gr < N) out[(size_t)gr * D + c * 16 + m16] = acc[c][j] + bv;
      }
    }
  }
}

// ---------------- launcher ----------------
extern "C" void kernel_launch(void* const* d_in, const int* in_sizes, int n_in,
                              void* d_out, int out_size, void* d_ws, size_t ws_size,
                              hipStream_t stream) {
  const int N = in_sizes[0] / D;   // 50000  (u16 CSR requires N <= 65536)
  const int E = in_sizes[1] / 2;   // 800000

  const float* x        = (const float*)d_in[0];
  const uint32_t* edges = (const uint32_t*)d_in[1];
  const float* W1  = (const float*)d_in[2];
  const float* b1  = (const float*)d_in[3];
  const float* Wmu = (const float*)d_in[4];
  const float* bmu = (const float*)d_in[5];
  const float* Wls = (const float*)d_in[6];
  const float* bls = (const float*)d_in[7];
  float* out_mu = (float*)d_out;
  float* out_ls = out_mu + (size_t)N * D;

  // workspace carve
  char* w = (char*)d_ws;
  uint32_t* deg    = (uint32_t*)(w);                  // N u32
  uint32_t* flag   = (uint32_t*)(w + (256u << 10));   // 1 u32
  uint32_t* bsum   = (uint32_t*)(w + (320u << 10));   // <=64 u32
  uint32_t* rowptr = (uint32_t*)(w + (512u << 10));   // N+1 u32
  uint32_t* cursor = (uint32_t*)(w + (768u << 10));   // N u32
  float*    dinv   = (float*)(w + (1u << 20));        // N f32 (200KB)
  _Float16* wT     = (_Float16*)(w + (1280u << 10));  // 3*128*128 f16 (96KB)
  uint32_t* packed = (uint32_t*)(w + (2u << 20));     // E u32 (3.2MB)
  uint16_t* csr    = (uint16_t*)(w + (6u << 20));     // E u16 (1.6MB)
  _Float16* G16    = (_Float16*)(w + (8u << 20));     // N*D f16 (conv1 GEMM out)
  _Float16* h16    = (_Float16*)(w + (21u << 20));    // N*D f16
  size_t need = (21u << 20) + (size_t)N * D * 2;
  if (ws_size < need || N > 65536) return;

  _Float16* wT1  = wT;
  _Float16* wTmu = wT + 128 * 128;
  _Float16* wTls = wT + 2 * 128 * 128;

  const int nDeg4 = (N + 3) / 4;
  const int nb = (N + 1023) / 1024;   // 49 for N=50000

  k_init<<<(nDeg4 + 255) / 256, 256, 0, stream>>>(edges, flag, (uint4*)deg, nDeg4,
                                                  W1, Wmu, Wls, wT);
  k_compact<<<(E + 255) / 256, 256, 0, stream>>>(edges, flag, packed, E);
  k_count<<<8 * 64, 256, 0, stream>>>(packed, deg, E, N);
  k_scan1<<<nb, 256, 0, stream>>>(deg, bsum, N);
  k_scan2<<<1, 64, 0, stream>>>(bsum, nb);
  k_scan3<<<nb, 256, 0, stream>>>(deg, bsum, rowptr, cursor, dinv, N, E);
  k_fill<<<8 * 128, 256, 0, stream>>>(packed, cursor, csr, E, N);

  const int gemmGrid = (N + 63) / 64;
  const int aggGrid  = ((N + 31) / 32) * 2;   // 2 column-halves

  // conv1: h = relu(Â(x@W1) + b1)
  k_gemm<<<gemmGrid, 256, 0, stream>>>(x, wT1, G16, N);
  k_agg<1, 1><<<aggGrid, 256, 0, stream>>>(G16, rowptr, csr, dinv, b1, h16, N);

  // fused: per 64-node tile, hagg = Â h into LDS, then dual GEMM -> out_mu/out_ls
  k_aggemm<<<gemmGrid, 256, 0, stream>>>(h16, rowptr, csr, dinv, wTmu, wTls,
                                         bmu, bls, out_mu, out_ls, N);
}